// Round 1
// baseline (471.891 us; speedup 1.0000x reference)
//
#include <hip/hip_runtime.h>

// Problem constants (from reference): B=64, T=4096, F=64, H=256, LAM=0.5, LAG=1, ALPHA=0.5, EPS=1e-8
constexpr int B = 64;
constexpr int T = 4096;
constexpr int F = 64;       // == wavefront size; lane <-> feature
constexpr int H = 256;
constexpr float EPSC = 1e-8f;
constexpr float ALPHAC = 0.5f;

constexpr int C = 128;              // scan chunk length
constexpr int W = 48;               // warmup steps (state error ~2^-48, negligible vs 3.9e-2 threshold)
constexpr int CHUNKS = T / C;       // 32 chunks per batch row

// ---------------------------------------------------------------------------
// K0: fg row-sums over H (one wave per row, float4 loads = exactly one 1KB row
// per wave-load) + fused MSE reduction. 268 MB stream -> memory-bound.
// ---------------------------------------------------------------------------
__global__ __launch_bounds__(256) void k_rowsum_mse(
    const float* __restrict__ fg,
    const float* __restrict__ inp,
    const float* __restrict__ tgt,
    float* __restrict__ fgsum,
    float* __restrict__ out) {
  const int lane = threadIdx.x & 63;
  const int wave = (blockIdx.x * blockDim.x + threadIdx.x) >> 6;
  const int nwaves = (gridDim.x * blockDim.x) >> 6;
  const int R = B * T;  // 262144 rows

  for (int r = wave; r < R; r += nwaves) {
    const float4 q = *reinterpret_cast<const float4*>(fg + (size_t)r * H + lane * 4);
    float s = (q.x + q.y) + (q.z + q.w);
#pragma unroll
    for (int off = 32; off; off >>= 1) s += __shfl_xor(s, off, 64);
    if (lane == 0) fgsum[r] = s;
  }

  // MSE partial (input/target are (B,T,1) -> R floats each)
  float acc = 0.f;
  const int tid = blockIdx.x * blockDim.x + threadIdx.x;
  const int nt = gridDim.x * blockDim.x;
  for (int i = tid; i < R; i += nt) {
    float d = inp[i] - tgt[i];
    acc = fmaf(d, d, acc);
  }
#pragma unroll
  for (int off = 32; off; off >>= 1) acc += __shfl_xor(acc, off, 64);
  __shared__ float sm[4];
  if ((threadIdx.x & 63) == 0) sm[threadIdx.x >> 6] = acc;
  __syncthreads();
  if (threadIdx.x == 0) {
    float s = (sm[0] + sm[1]) + (sm[2] + sm[3]);
    atomicAdd(out, s / (float)R);
  }
}

// ---------------------------------------------------------------------------
// K1: chunked EWA scan. Task = (b, chunk). lane = feature f. Coalesced 256B
// per t-step. Warmup W steps from zero state (lambda=0.5 => 2^-48 state error).
// Accumulate (1-|ac_f|) * fgsum[b,t] per lane over t; one butterfly + one
// atomicAdd per wave.
// ---------------------------------------------------------------------------
__global__ __launch_bounds__(256) void k_scan(
    const float* __restrict__ seq,
    const float* __restrict__ fgsum,
    float* __restrict__ out) {
  const int lane = threadIdx.x & 63;
  const int task = blockIdx.x * (blockDim.x >> 6) + (threadIdx.x >> 6);
  const int b = task / CHUNKS;
  const int ci = task % CHUNKS;
  const int t0 = ci * C;

  const float* sp = seq + (size_t)b * T * F + lane;  // index with + t*F
  const float* fp = fgsum + (size_t)b * T;

  float m = 0.f, v = 0.f, c = 0.f;
  float acc = 0.f;
  float xl;
  int t;

  if (ci == 0) {
    // exact initial state: m=0, v=EPS, c=0; t=0 has ac=0 -> contribution 1*fgsum
    v = EPSC;
    acc = fp[0];
    xl = sp[0];
    t = 1;
  } else {
    const int ts = t0 - W;
    xl = sp[(ts - 1) * F];
    for (t = ts; t < t0; ++t) {
      const float xt = sp[t * F];
      m = 0.5f * (m + xt);
      const float d = xt - m;
      v = 0.5f * fmaf(d, d, v);
      c = 0.5f * fmaf(d, xl - m, c);
      xl = xt;
    }
  }

  const int tend = t0 + C;
  for (; t < tend; ++t) {
    const float xt = sp[t * F];
    const float g = fp[t];  // same-address across wave -> broadcast
    m = 0.5f * (m + xt);
    const float d = xt - m;
    v = 0.5f * fmaf(d, d, v);
    c = 0.5f * fmaf(d, xl - m, c);
    const float ac = c * rsqrtf(fmaf(v, v, EPSC));
    acc = fmaf(1.0f - fabsf(ac), g, acc);
    xl = xt;
  }

#pragma unroll
  for (int off = 32; off; off >>= 1) acc += __shfl_xor(acc, off, 64);
  if (lane == 0) {
    const float scale = ALPHAC / ((float)B * (float)T * (float)H * (float)F);
    atomicAdd(out, acc * scale);
  }
}

extern "C" void kernel_launch(void* const* d_in, const int* in_sizes, int n_in,
                              void* d_out, int out_size, void* d_ws, size_t ws_size,
                              hipStream_t stream) {
  const float* inp = (const float*)d_in[0];   // (B,T,1)
  const float* tgt = (const float*)d_in[1];   // (B,T,1)
  const float* seq = (const float*)d_in[2];   // (B,T,F)
  const float* fg  = (const float*)d_in[3];   // (B,T,H)
  float* out = (float*)d_out;                 // scalar
  float* fgsum = (float*)d_ws;                // B*T floats = 1 MB

  // d_out is poisoned 0xAA before every timed launch -> zero it on stream.
  hipMemsetAsync(out, 0, sizeof(float), stream);

  // K0: 2048 blocks x 256 = 8192 waves streaming 268 MB
  k_rowsum_mse<<<2048, 256, 0, stream>>>(fg, inp, tgt, fgsum, out);

  // K1: B*CHUNKS = 2048 wave-tasks, 4 waves/block -> 512 blocks
  k_scan<<<(B * CHUNKS) / 4, 256, 0, stream>>>(seq, fgsum, out);
}

// Round 2
// 446.434 us; speedup vs baseline: 1.0570x; 1.0570x over previous
//
#include <hip/hip_runtime.h>

// Problem constants: B=64, T=4096, F=64, H=256, LAM=0.5, LAG=1, ALPHA=0.5, EPS=1e-8
constexpr int B = 64;
constexpr int T = 4096;
constexpr int F = 64;       // == wavefront size; lane <-> feature
constexpr int H = 256;
constexpr float EPSC = 1e-8f;
constexpr float ALPHAC = 0.5f;

constexpr int C = 128;              // scan chunk length
constexpr int W = 48;               // warmup steps (lambda=0.5 -> 2^-48 state error)
constexpr int CHUNKS = T / C;       // 32 chunks per batch row

constexpr int K0_BLOCKS = 2048;
constexpr int K1_BLOCKS = (B * CHUNKS) / 4;   // 512 blocks x 4 waves = 2048 wave-tasks

// ws layout (floats): [0, B*T)              fgsum
//                     [B*T, B*T+2048)       mse partials (per k0 block)
//                     [B*T+2048, +2048)     penalty partials (per k1 wave)
#define WS_FGSUM 0
#define WS_MSE   (B * T)
#define WS_PEN   (B * T + K0_BLOCKS)

// ---------------------------------------------------------------------------
// K0: fg row-sums over H (one wave per row, float4 loads) + fused MSE partial.
// NO atomics: one partial store per block.
// ---------------------------------------------------------------------------
__global__ __launch_bounds__(256) void k_rowsum_mse(
    const float* __restrict__ fg,
    const float* __restrict__ inp,
    const float* __restrict__ tgt,
    float* __restrict__ ws) {
  float* fgsum = ws + WS_FGSUM;
  const int lane = threadIdx.x & 63;
  const int wave = (blockIdx.x * blockDim.x + threadIdx.x) >> 6;
  const int nwaves = (gridDim.x * blockDim.x) >> 6;
  const int R = B * T;  // 262144 rows

  for (int r = wave; r < R; r += nwaves) {
    const float4 q = *reinterpret_cast<const float4*>(fg + (size_t)r * H + lane * 4);
    float s = (q.x + q.y) + (q.z + q.w);
#pragma unroll
    for (int off = 32; off; off >>= 1) s += __shfl_xor(s, off, 64);
    if (lane == 0) fgsum[r] = s;
  }

  // MSE partial (input/target are (B,T,1) -> R floats each)
  float acc = 0.f;
  const int tid = blockIdx.x * blockDim.x + threadIdx.x;
  const int nt = gridDim.x * blockDim.x;
  for (int i = tid; i < R; i += nt) {
    float d = inp[i] - tgt[i];
    acc = fmaf(d, d, acc);
  }
#pragma unroll
  for (int off = 32; off; off >>= 1) acc += __shfl_xor(acc, off, 64);
  __shared__ float sm[4];
  if ((threadIdx.x & 63) == 0) sm[threadIdx.x >> 6] = acc;
  __syncthreads();
  if (threadIdx.x == 0)
    ws[WS_MSE + blockIdx.x] = (sm[0] + sm[1]) + (sm[2] + sm[3]);
}

// ---------------------------------------------------------------------------
// K1: chunked EWA scan. Task = (b, chunk). lane = feature f. Coalesced 256B
// per t-step. NO atomics: one partial store per wave.
// ---------------------------------------------------------------------------
__global__ __launch_bounds__(256) void k_scan(
    const float* __restrict__ seq,
    float* __restrict__ ws) {
  const float* fgsum = ws + WS_FGSUM;
  const int lane = threadIdx.x & 63;
  const int task = blockIdx.x * (blockDim.x >> 6) + (threadIdx.x >> 6);
  const int b = task / CHUNKS;
  const int ci = task % CHUNKS;
  const int t0 = ci * C;

  const float* sp = seq + (size_t)b * T * F + lane;  // index with + t*F
  const float* fp = fgsum + (size_t)b * T;

  float m = 0.f, v = 0.f, c = 0.f;
  float acc = 0.f;
  float xl;
  int t;

  if (ci == 0) {
    // exact initial state: m=0, v=EPS, c=0; t=0 has ac=0 -> contribution 1*fgsum
    v = EPSC;
    acc = fp[0];
    xl = sp[0];
    t = 1;
  } else {
    const int ts = t0 - W;
    xl = sp[(ts - 1) * F];
    for (t = ts; t < t0; ++t) {
      const float xt = sp[t * F];
      m = 0.5f * (m + xt);
      const float d = xt - m;
      v = 0.5f * fmaf(d, d, v);
      c = 0.5f * fmaf(d, xl - m, c);
      xl = xt;
    }
  }

  const int tend = t0 + C;
  for (; t < tend; ++t) {
    const float xt = sp[t * F];
    const float g = fp[t];  // same-address across wave -> broadcast
    m = 0.5f * (m + xt);
    const float d = xt - m;
    v = 0.5f * fmaf(d, d, v);
    c = 0.5f * fmaf(d, xl - m, c);
    const float ac = c * rsqrtf(fmaf(v, v, EPSC));
    acc = fmaf(1.0f - fabsf(ac), g, acc);
    xl = xt;
  }

#pragma unroll
  for (int off = 32; off; off >>= 1) acc += __shfl_xor(acc, off, 64);
  if (lane == 0) ws[WS_PEN + task] = acc;
}

// ---------------------------------------------------------------------------
// K2: final reduce of 2048 mse partials + 2048 penalty partials (16 KB, L2-hot).
// ---------------------------------------------------------------------------
__global__ __launch_bounds__(256) void k_reduce(
    const float* __restrict__ ws,
    float* __restrict__ out) {
  float m = 0.f, p = 0.f;
#pragma unroll
  for (int i = 0; i < K0_BLOCKS / 256; ++i)
    m += ws[WS_MSE + threadIdx.x + i * 256];
#pragma unroll
  for (int i = 0; i < 2048 / 256; ++i)
    p += ws[WS_PEN + threadIdx.x + i * 256];
#pragma unroll
  for (int off = 32; off; off >>= 1) {
    m += __shfl_xor(m, off, 64);
    p += __shfl_xor(p, off, 64);
  }
  __shared__ float sm[8];
  if ((threadIdx.x & 63) == 0) {
    sm[(threadIdx.x >> 6) * 2]     = m;
    sm[(threadIdx.x >> 6) * 2 + 1] = p;
  }
  __syncthreads();
  if (threadIdx.x == 0) {
    float mt = sm[0] + sm[2] + sm[4] + sm[6];
    float pt = sm[1] + sm[3] + sm[5] + sm[7];
    const float R = (float)B * (float)T;
    const float pscale = ALPHAC / (R * (float)H * (float)F);
    out[0] = mt / R + pt * pscale;
  }
}

extern "C" void kernel_launch(void* const* d_in, const int* in_sizes, int n_in,
                              void* d_out, int out_size, void* d_ws, size_t ws_size,
                              hipStream_t stream) {
  const float* inp = (const float*)d_in[0];   // (B,T,1)
  const float* tgt = (const float*)d_in[1];   // (B,T,1)
  const float* seq = (const float*)d_in[2];   // (B,T,F)
  const float* fg  = (const float*)d_in[3];   // (B,T,H)
  float* out = (float*)d_out;                 // scalar
  float* ws  = (float*)d_ws;

  k_rowsum_mse<<<K0_BLOCKS, 256, 0, stream>>>(fg, inp, tgt, ws);
  k_scan<<<K1_BLOCKS, 256, 0, stream>>>(seq, ws);
  k_reduce<<<1, 256, 0, stream>>>(ws, out);
}

// Round 3
// 407.257 us; speedup vs baseline: 1.1587x; 1.0962x over previous
//
#include <hip/hip_runtime.h>

// Problem constants: B=64, T=4096, F=64, H=256, LAM=0.5, LAG=1, ALPHA=0.5, EPS=1e-8
constexpr int B = 64;
constexpr int T = 4096;
constexpr int F = 64;       // == wavefront size; lane <-> feature
constexpr int H = 256;
constexpr float EPSC = 1e-8f;
constexpr float ALPHAC = 0.5f;

constexpr int C = 128;              // scan chunk length (one wave-task per chunk)
constexpr int W = 48;               // warmup steps (lambda=0.5 -> 2^-48 state error)
constexpr int CHUNKS = T / C;       // 32 chunks per batch row
constexpr int NTASK = B * CHUNKS;   // 2048 wave-tasks
constexpr int K_BLOCKS = NTASK / 4; // 512 blocks x 4 waves

// ws layout (floats): [0, 2048) penalty partials (per wave), [2048, 2560) mse partials (per block)
#define WS_PEN 0
#define WS_MSE NTASK

// ---------------------------------------------------------------------------
// Fused kernel: per wave-task (b, chunk) run the EWA scan over 128 t-steps.
// Per step: load the 1 KB fg row (float4/lane, coalesced), butterfly-reduce to
// fgsum_t, load 256 B of seq, do the scan update, accumulate (1-|ac|)*fgsum_t
// per lane. fg is read exactly once across all tasks (chunks partition t).
// Depth-4 rotating register prefetch keeps ~5 KB in flight per wave.
// MSE folded in as a grid-stride tail. No atomics: one partial per wave/block.
// ---------------------------------------------------------------------------
__global__ __launch_bounds__(256) void k_fused(
    const float* __restrict__ seq,
    const float* __restrict__ fg,
    const float* __restrict__ inp,
    const float* __restrict__ tgt,
    float* __restrict__ ws) {
  const int lane = threadIdx.x & 63;
  const int task = blockIdx.x * (blockDim.x >> 6) + (threadIdx.x >> 6);
  const int b = task / CHUNKS;
  const int ci = task % CHUNKS;
  const int t0 = ci * C;
  const int tend = t0 + C;

  const float* sp = seq + (size_t)b * T * F + lane;        // + t*F
  const float* gp = fg + (size_t)b * T * H + lane * 4;     // + t*H (float4)

  float m = 0.f, v = 0.f, c = 0.f, acc = 0.f;
  float xl = 0.f;

  if (ci == 0) {
    v = EPSC;  // exact initial state; t=0 handled in-loop (ac=0 contribution)
  } else {
    // warmup: 48 seq-only steps, pipelined depth 4 (fully unrolled, const trip)
    const int ts = t0 - W;
    xl = sp[(ts - 1) * F];
    float xw[4];
#pragma unroll
    for (int j = 0; j < 4; ++j) xw[j] = sp[(ts + j) * F];
#pragma unroll
    for (int i = 0; i < W; ++i) {
      const float xt = xw[i & 3];
      if (i + 4 < W) xw[i & 3] = sp[(ts + i + 4) * F];
      m = 0.5f * (m + xt);
      const float d = xt - m;
      v = 0.5f * fmaf(d, d, v);
      c = 0.5f * fmaf(d, xl - m, c);
      xl = xt;
    }
  }

  // main loop: exactly C steps for every task (chunk 0 starts at t=0 with a
  // wave-uniform scalar branch for the pad step). Prefetch depth 4.
  const int tstart = t0;
  float4 qb[4];
  float xb[4];
#pragma unroll
  for (int j = 0; j < 4; ++j) {
    qb[j] = *reinterpret_cast<const float4*>(gp + (size_t)(tstart + j) * H);
    xb[j] = sp[(tstart + j) * F];
  }

#pragma unroll 4
  for (int i = 0; i < C; ++i) {
    const int tt = tstart + i;
    const float4 q = qb[i & 3];
    const float xt = xb[i & 3];
    int tp = tt + 4;
    tp = (tp < tend) ? tp : (tend - 1);   // clamped re-load at tail (L1-hot)
    qb[i & 3] = *reinterpret_cast<const float4*>(gp + (size_t)tp * H);
    xb[i & 3] = sp[tp * F];

    // fg row-sum -> broadcast to all lanes
    float s = (q.x + q.y) + (q.z + q.w);
#pragma unroll
    for (int off = 32; off; off >>= 1) s += __shfl_xor(s, off, 64);

    if (tt != 0) {          // wave-uniform (only chunk 0 ever sees tt==0)
      m = 0.5f * (m + xt);
      const float d = xt - m;
      v = 0.5f * fmaf(d, d, v);
      c = 0.5f * fmaf(d, xl - m, c);
      const float ac = c * rsqrtf(fmaf(v, v, EPSC));
      acc = fmaf(1.0f - fabsf(ac), s, acc);
    } else {
      acc += s;             // t=0: ac=0 -> irrelevance=1; state stays initial
    }
    xl = xt;
  }

#pragma unroll
  for (int off = 32; off; off >>= 1) acc += __shfl_xor(acc, off, 64);
  if (lane == 0) ws[WS_PEN + task] = acc;

  // ---- MSE partial (input/target are (B,T,1) -> B*T floats each) ----
  float macc = 0.f;
  const int gid = blockIdx.x * blockDim.x + threadIdx.x;
  const int nt = gridDim.x * blockDim.x;
  const int R = B * T;
  for (int i = gid; i < R; i += nt) {
    const float d = inp[i] - tgt[i];
    macc = fmaf(d, d, macc);
  }
#pragma unroll
  for (int off = 32; off; off >>= 1) macc += __shfl_xor(macc, off, 64);
  __shared__ float sm[4];
  if ((threadIdx.x & 63) == 0) sm[threadIdx.x >> 6] = macc;
  __syncthreads();
  if (threadIdx.x == 0)
    ws[WS_MSE + blockIdx.x] = (sm[0] + sm[1]) + (sm[2] + sm[3]);
}

// ---------------------------------------------------------------------------
// Final reduce: 2048 penalty partials + 512 mse partials (10 KB, L2-hot).
// ---------------------------------------------------------------------------
__global__ __launch_bounds__(256) void k_reduce(
    const float* __restrict__ ws,
    float* __restrict__ out) {
  float p = 0.f, mt = 0.f;
#pragma unroll
  for (int i = 0; i < NTASK / 256; ++i)
    p += ws[WS_PEN + threadIdx.x + i * 256];
#pragma unroll
  for (int i = 0; i < K_BLOCKS / 256; ++i)
    mt += ws[WS_MSE + threadIdx.x + i * 256];
#pragma unroll
  for (int off = 32; off; off >>= 1) {
    p += __shfl_xor(p, off, 64);
    mt += __shfl_xor(mt, off, 64);
  }
  __shared__ float sm[8];
  if ((threadIdx.x & 63) == 0) {
    sm[(threadIdx.x >> 6) * 2] = p;
    sm[(threadIdx.x >> 6) * 2 + 1] = mt;
  }
  __syncthreads();
  if (threadIdx.x == 0) {
    const float pt = sm[0] + sm[2] + sm[4] + sm[6];
    const float ms = sm[1] + sm[3] + sm[5] + sm[7];
    const float R = (float)B * (float)T;
    const float pscale = ALPHAC / (R * (float)H * (float)F);
    out[0] = ms / R + pt * pscale;
  }
}

extern "C" void kernel_launch(void* const* d_in, const int* in_sizes, int n_in,
                              void* d_out, int out_size, void* d_ws, size_t ws_size,
                              hipStream_t stream) {
  const float* inp = (const float*)d_in[0];   // (B,T,1)
  const float* tgt = (const float*)d_in[1];   // (B,T,1)
  const float* seq = (const float*)d_in[2];   // (B,T,F)
  const float* fg  = (const float*)d_in[3];   // (B,T,H)
  float* out = (float*)d_out;                 // scalar
  float* ws  = (float*)d_ws;

  k_fused<<<K_BLOCKS, 256, 0, stream>>>(seq, fg, inp, tgt, ws);
  k_reduce<<<1, 256, 0, stream>>>(ws, out);
}